// Round 3
// baseline (12812.801 us; speedup 1.0000x reference)
//
#include <hip/hip_runtime.h>
#include <hip/hip_bf16.h>

#define HH 192
#define WW 192
#define HW (HH*WW)

typedef unsigned short u16;

__device__ __forceinline__ float b2f(u16 u){
  union { unsigned int i; float f; } v; v.i = ((unsigned int)u) << 16; return v.f;
}
__device__ __forceinline__ u16 f2b(float f){
  union { unsigned int i; float f; } v; v.f = f;
  unsigned int r = v.i + 0x7FFFu + ((v.i >> 16) & 1u);
  return (u16)(r >> 16);
}
__device__ __forceinline__ void up2(unsigned int w, float& lo, float& hi){
  union { unsigned int i; float f; } a, b;
  a.i = w << 16; b.i = w & 0xFFFF0000u;
  lo = a.f; hi = b.f;
}
__device__ __forceinline__ float lrelu(float x){ return x >= 0.f ? x : 0.1f*x; }
__device__ __forceinline__ float ldmix(const void* p, int i, bool bf){
  return bf ? b2f(((const u16*)p)[i]) : ((const float*)p)[i];
}

// Dtype detector: bf16-packed => low u16 of each u32 has exponent in (100,150)
// ~always; fp32 => low u16 is random mantissa bits (~19% hit rate).
__global__ __launch_bounds__(256) void detect_k(const unsigned int* __restrict__ w, int* __restrict__ flag){
  __shared__ int cnt;
  if (threadIdx.x == 0) cnt = 0;
  __syncthreads();
  unsigned int v = w[(size_t)threadIdx.x * 1024];
  int e = (v >> 7) & 0xFF;
  bool ok = ((v & 0xFFFFu) == 0u) || (e > 100 && e < 150);
  if (ok) atomicAdd(&cnt, 1);
  __syncthreads();
  if (threadIdx.x == 0) *flag = (cnt >= 192) ? 1 : 0;
}

__global__ __launch_bounds__(256) void cvt_io(const void* __restrict__ pred, const void* __restrict__ refp,
                                              float* __restrict__ dst, const int* __restrict__ flag){
  int i = blockIdx.x*256 + threadIdx.x;
  bool bf = (*flag != 0);
  const int n = 9437184;
  const void* src = (i < n) ? pred : refp;
  int j = (i < n) ? i : i - n;
  dst[i] = ldmix(src, j, bf);
}

__global__ __launch_bounds__(256) void prep_w(const void* __restrict__ w1, const void* __restrict__ w2,
                                              const void* __restrict__ wr, const void* __restrict__ wp,
                                              const void* __restrict__ b1, const void* __restrict__ b2,
                                              const void* __restrict__ rb,
                                              float* __restrict__ w1f, float* __restrict__ w2f,
                                              float* __restrict__ wrf, float* __restrict__ wpf,
                                              float* __restrict__ b1f, float* __restrict__ b2f,
                                              float* __restrict__ rbf, const int* __restrict__ flag){
  int i = blockIdx.x*256 + threadIdx.x;
  bool bf = (*flag != 0);
  if (i < 36864){ int co = i & 63;  int t = i >> 6; int ci = t & 63; int tap = t >> 6;
    w1f[(tap*64+ci)*64+co]  = ldmix(w1, (co*64+ci)*9+tap, bf); }
  if (i < 73728){ int co = i & 127; int t = i >> 7; int ci = t & 63; int tap = t >> 6;
    w2f[(tap*64+ci)*128+co] = ldmix(w2, (co*64+ci)*9+tap, bf); }
  if (i < 4096){ int co = i & 31; int ci = i >> 5;
    wrf[ci*32+co] = ldmix(wr, co*128+ci, bf); }
  if (i < 8514){ int o = i & 1; int t = i >> 1; int c = t % 473; int tap = t / 473;
    wpf[tap*948 + c*2 + o] = ldmix(wp, (o*473+c)*9+tap, bf); }
  if (i < 64)  b1f[i] = ldmix(b1, i, bf);
  if (i < 128) b2f[i] = ldmix(b2, i, bf);
  if (i < 32)  rbf[i] = ldmix(rb, i, bf);
}

template<int CIN, int COUT, bool FP32_NCHW>
__global__ __launch_bounds__(256) void conv3x3_k(const void* __restrict__ in, const float* __restrict__ wf,
                                                 const float* __restrict__ bias, u16* __restrict__ out){
  constexpr int CB = COUT/64;
  __shared__ __align__(16) float s_in[8][18][20];
  __shared__ __align__(16) float s_w[9][8][64];
  int tid = threadIdx.x;
  int bx = blockIdx.x, by = blockIdx.y;
  int b8 = (int)blockIdx.z / CB, cob = (int)blockIdx.z % CB;
  int co0 = cob*64;
  size_t boff = (size_t)b8*HW*CIN;
  int ty = tid >> 4, cg = tid & 15;
  float4 acc[16];
  #pragma unroll
  for (int i=0;i<16;i++) acc[i] = make_float4(0.f,0.f,0.f,0.f);

  for (int ci0 = 0; ci0 < CIN; ci0 += 8){
    if (ci0) __syncthreads();
    for (int e = tid; e < 8*324; e += 256){
      int ci, r, c;
      if (FP32_NCHW){ ci = e / 324; int pp = e - ci*324; r = pp/18; c = pp - r*18; }
      else          { ci = e & 7;   int pp = e >> 3;     r = pp/18; c = pp - r*18; }
      int gy = by*16 + r - 1, gx = bx*16 + c - 1;
      float v = 0.f;
      if (gy >= 0 && gy < HH && gx >= 0 && gx < WW){
        if (FP32_NCHW) v = ((const float*)in)[boff + (size_t)(ci0+ci)*HW + (size_t)gy*WW + gx];
        else           v = b2f(((const u16*)in)[boff + ((size_t)gy*WW + gx)*CIN + ci0 + ci]);
      }
      s_in[ci][r][c] = v;
    }
    for (int e = tid; e < 9*8*64; e += 256){
      int co = e & 63; int t = e >> 6; int cl = t & 7; int tap = t >> 3;
      s_w[tap][cl][co] = wf[(size_t)(tap*CIN + ci0 + cl)*COUT + co0 + co];
    }
    __syncthreads();
    for (int cl = 0; cl < 8; ++cl){
      #pragma unroll
      for (int ky = 0; ky < 3; ++ky){
        const float* rp = &s_in[cl][ty+ky][0];
        float row[18];
        *(float4*)&row[0]  = *(const float4*)(rp);
        *(float4*)&row[4]  = *(const float4*)(rp+4);
        *(float4*)&row[8]  = *(const float4*)(rp+8);
        *(float4*)&row[12] = *(const float4*)(rp+12);
        *(float2*)&row[16] = *(const float2*)(rp+16);
        #pragma unroll
        for (int kx = 0; kx < 3; ++kx){
          float4 wv = *(const float4*)&s_w[ky*3+kx][cl][cg*4];
          #pragma unroll
          for (int px = 0; px < 16; ++px){
            float a = row[px+kx];
            acc[px].x += a*wv.x; acc[px].y += a*wv.y;
            acc[px].z += a*wv.z; acc[px].w += a*wv.w;
          }
        }
      }
    }
  }
  int gy = by*16 + ty;
  float bv0 = bias[co0+cg*4+0], bv1 = bias[co0+cg*4+1];
  float bv2 = bias[co0+cg*4+2], bv3 = bias[co0+cg*4+3];
  u16* op = out + ((size_t)b8*HW + (size_t)gy*WW + bx*16)*COUT + co0 + cg*4;
  #pragma unroll
  for (int px = 0; px < 16; ++px){
    float v0 = lrelu(acc[px].x + bv0);
    float v1 = lrelu(acc[px].y + bv1);
    float v2 = lrelu(acc[px].z + bv2);
    float v3 = lrelu(acc[px].w + bv3);
    uint2 pk;
    pk.x = (unsigned int)f2b(v0) | ((unsigned int)f2b(v1) << 16);
    pk.y = (unsigned int)f2b(v2) | ((unsigned int)f2b(v3) << 16);
    *(uint2*)(op + (size_t)px*COUT) = pk;
  }
}

__global__ __launch_bounds__(256) void redir_k(const u16* __restrict__ C2, const float* __restrict__ wrf,
                                               const float* __restrict__ rbf, u16* __restrict__ X){
  int p = blockIdx.x*256 + threadIdx.x;
  const u16* ap = C2 + (size_t)p*128;
  float acc[32];
  #pragma unroll
  for (int j=0;j<32;j++) acc[j]=0.f;
  for (int ci=0; ci<128; ci+=4){
    uint2 aw = *(const uint2*)(ap + ci);
    float a0,a1,a2,a3;
    up2(aw.x,a0,a1); up2(aw.y,a2,a3);
    const float* w0 = wrf + ci*32;
    #pragma unroll
    for (int co=0; co<32; co+=4){
      float4 wv0 = *(const float4*)(w0+co);
      float4 wv1 = *(const float4*)(w0+32+co);
      float4 wv2 = *(const float4*)(w0+64+co);
      float4 wv3 = *(const float4*)(w0+96+co);
      acc[co+0] += a0*wv0.x + a1*wv1.x + a2*wv2.x + a3*wv3.x;
      acc[co+1] += a0*wv0.y + a1*wv1.y + a2*wv2.y + a3*wv3.y;
      acc[co+2] += a0*wv0.z + a1*wv1.z + a2*wv2.z + a3*wv3.z;
      acc[co+3] += a0*wv0.w + a1*wv1.w + a2*wv2.w + a3*wv3.w;
    }
  }
  u16* xp = X + (size_t)p*480;
  #pragma unroll
  for (int co=0; co<32; co+=8){
    float v[8];
    #pragma unroll
    for (int j=0;j<8;j++) v[j] = lrelu(acc[co+j] + rbf[co+j]);
    uint4 pk;
    pk.x = (unsigned int)f2b(v[0]) | ((unsigned int)f2b(v[1]) << 16);
    pk.y = (unsigned int)f2b(v[2]) | ((unsigned int)f2b(v[3]) << 16);
    pk.z = (unsigned int)f2b(v[4]) | ((unsigned int)f2b(v[5]) << 16);
    pk.w = (unsigned int)f2b(v[6]) | ((unsigned int)f2b(v[7]) << 16);
    *(uint4*)(xp + co) = pk;
  }
}

#define CPAD 72
__global__ __launch_bounds__(192) void corr_k(const u16* __restrict__ C2, u16* __restrict__ X){
  __shared__ __align__(16) u16 seg[232*CPAD];
  int tid = threadIdx.x;
  int y = blockIdx.y;
  int z = blockIdx.z;
  int b = z / 21, dy = z - b*21;
  int r = y + 2*dy - 20;
  int x = tid;
  u16* xp = X + ((size_t)b*HW + (size_t)y*WW + x)*480 + 32 + dy*21;
  if (r < 0 || r >= HH){
    #pragma unroll
    for (int dx=0; dx<21; ++dx) xp[dx] = 0;
    return;
  }
  const u16* arow = C2 + ((size_t)b*HW + (size_t)y*WW + x)*128;
  const u16* brow = C2 + ((size_t)(b+4)*HW + (size_t)r*WW)*128;
  float acc[21];
  #pragma unroll
  for (int dx=0; dx<21; ++dx) acc[dx]=0.f;

  for (int half=0; half<2; ++half){
    int cb = half*64;
    if (half) __syncthreads();
    for (int e = tid; e < 232*64; e += 192){
      int ch = e & 63, pos = e >> 6;
      int gx = pos - 20;
      u16 v = 0;
      if (gx >= 0 && gx < WW) v = brow[(size_t)gx*128 + cb + ch];
      seg[pos*CPAD + ch] = v;
    }
    __syncthreads();
    float av[64];
    #pragma unroll
    for (int i=0;i<8;i++){
      uint4 aw = *(const uint4*)(arow + cb + i*8);
      up2(aw.x, av[i*8+0], av[i*8+1]);
      up2(aw.y, av[i*8+2], av[i*8+3]);
      up2(aw.z, av[i*8+4], av[i*8+5]);
      up2(aw.w, av[i*8+6], av[i*8+7]);
    }
    #pragma unroll
    for (int dx=0; dx<21; ++dx){
      const u16* sp = seg + (tid + 2*dx)*CPAD;
      float s0=0.f,s1=0.f,s2=0.f,s3=0.f;
      #pragma unroll
      for (int i=0;i<8;i++){
        uint4 bw = *(const uint4*)(sp + i*8);
        float l,h;
        up2(bw.x,l,h); s0 += av[i*8+0]*l; s0 += av[i*8+1]*h;
        up2(bw.y,l,h); s1 += av[i*8+2]*l; s1 += av[i*8+3]*h;
        up2(bw.z,l,h); s2 += av[i*8+4]*l; s2 += av[i*8+5]*h;
        up2(bw.w,l,h); s3 += av[i*8+6]*l; s3 += av[i*8+7]*h;
      }
      acc[dx] += (s0+s1)+(s2+s3);
    }
  }
  #pragma unroll
  for (int dx=0; dx<21; ++dx){
    xp[dx] = f2b(lrelu(acc[dx]*(1.f/128.f)));
  }
}

// Final 3x3 conv over 473-ch concat; dtype of output driven by flag.
__global__ __launch_bounds__(256) void final_k(const u16* __restrict__ X, const float* __restrict__ wpf,
                                               void* __restrict__ out, const int* __restrict__ flag){
  int p = blockIdx.x*256 + threadIdx.x;
  int b = p / HW; int rem = p - b*HW; int y = rem / WW; int x = rem - y*WW;
  float a0 = 0.f, a1 = 0.f;
  for (int ky=0; ky<3; ++ky){
    int gy = y + ky - 1;
    if (gy < 0 || gy >= HH) continue;
    for (int kx=0; kx<3; ++kx){
      int gx = x + kx - 1;
      if (gx < 0 || gx >= WW) continue;
      const u16* xrow = X + ((size_t)b*HW + (size_t)gy*WW + gx)*480;
      const float* wt = wpf + (ky*3+kx)*948;
      for (int c8 = 0; c8 < 472; c8 += 8){
        uint4 xw = *(const uint4*)(xrow + c8);
        float v0,v1,v2,v3,v4,v5,v6,v7;
        up2(xw.x,v0,v1); up2(xw.y,v2,v3); up2(xw.z,v4,v5); up2(xw.w,v6,v7);
        float4 w0 = *(const float4*)(wt + c8*2);
        float4 w1 = *(const float4*)(wt + c8*2 + 4);
        float4 w2 = *(const float4*)(wt + c8*2 + 8);
        float4 w3 = *(const float4*)(wt + c8*2 + 12);
        a0 += v0*w0.x + v1*w0.z + v2*w1.x + v3*w1.z + v4*w2.x + v5*w2.z + v6*w3.x + v7*w3.z;
        a1 += v0*w0.y + v1*w0.w + v2*w1.y + v3*w1.w + v4*w2.y + v5*w2.w + v6*w3.y + v7*w3.w;
      }
      float v = b2f(xrow[472]);
      a0 += v*wt[944]; a1 += v*wt[945];
    }
  }
  size_t i0 = (size_t)(b*2)*HW + rem;
  size_t i1 = (size_t)(b*2+1)*HW + rem;
  if (*flag){  // bf16 I/O
    ((u16*)out)[i0] = f2b(a0);
    ((u16*)out)[i1] = f2b(a1);
  } else {     // fp32 I/O
    ((float*)out)[i0] = a0;
    ((float*)out)[i1] = a1;
  }
}

// Workspace layout (bytes):
//   [0, 75497472)         predf fp32 [8][64][HW] (dies after conv1); then C2 bf16 [8][HW][128]
//   [75497472, 113246208) A: conv1 out bf16 [8][HW][64] (dies after conv2)
//   [75497472, 217055232) X: concat bf16 [4][HW][480] (reuses A region)
//   [217055232, ...)      fp32 weights + biases + flag (~495 KB)
extern "C" void kernel_launch(void* const* d_in, const int* in_sizes, int n_in,
                              void* d_out, int out_size, void* d_ws, size_t ws_size,
                              hipStream_t stream){
  char* ws = (char*)d_ws;
  float* predf = (float*)ws;
  u16* C2 = (u16*)ws;
  u16* A  = (u16*)(ws + 75497472);
  u16* X  = (u16*)(ws + 75497472);
  float* w1f = (float*)(ws + 217055232);
  float* w2f = w1f + 9*64*64;
  float* wrf = w2f + 9*64*128;
  float* wpf = wrf + 128*32;
  float* b1f = wpf + 9*948;
  float* b2f = b1f + 64;
  float* rbf = b2f + 128;
  int* flag  = (int*)(rbf + 32);

  detect_k<<<1,256,0,stream>>>((const unsigned int*)d_in[0], flag);
  cvt_io<<<73728,256,0,stream>>>(d_in[0], d_in[1], predf, flag);
  prep_w<<<288,256,0,stream>>>(d_in[2], d_in[4], d_in[6], d_in[8],
                               d_in[3], d_in[5], d_in[7],
                               w1f, w2f, wrf, wpf, b1f, b2f, rbf, flag);
  conv3x3_k<64,64,true  ><<<dim3(12,12,8), 256,0,stream>>>(predf, w1f, b1f, A);
  conv3x3_k<64,128,false><<<dim3(12,12,16),256,0,stream>>>(A, w2f, b2f, C2);
  redir_k<<<576,256,0,stream>>>(C2, wrf, rbf, X);
  corr_k<<<dim3(1,192,84),192,0,stream>>>(C2, X);
  final_k<<<576,256,0,stream>>>(X, wpf, d_out, flag);
}

// Round 4
// 12231.229 us; speedup vs baseline: 1.0475x; 1.0475x over previous
//
#include <hip/hip_runtime.h>
#include <hip/hip_bf16.h>

#define HH 192
#define WW 192
#define HW (HH*WW)

typedef unsigned short u16;

__device__ __forceinline__ float b2f(u16 u){
  union { unsigned int i; float f; } v; v.i = ((unsigned int)u) << 16; return v.f;
}
__device__ __forceinline__ u16 f2b(float f){
  union { unsigned int i; float f; } v; v.f = f;
  unsigned int r = v.i + 0x7FFFu + ((v.i >> 16) & 1u);
  return (u16)(r >> 16);
}
__device__ __forceinline__ void up2(unsigned int w, float& lo, float& hi){
  union { unsigned int i; float f; } a, b;
  a.i = w << 16; b.i = w & 0xFFFF0000u;
  lo = a.f; hi = b.f;
}
__device__ __forceinline__ float lrelu(float x){ return x >= 0.f ? x : 0.1f*x; }
__device__ __forceinline__ float ldmix(const void* p, int i, bool bf){
  return bf ? b2f(((const u16*)p)[i]) : ((const float*)p)[i];
}

// Dtype detector (fp32 vs bf16 inputs) — round-3 evidence says fp32, keep robust.
__global__ __launch_bounds__(256) void detect_k(const unsigned int* __restrict__ w, int* __restrict__ flag){
  __shared__ int cnt;
  if (threadIdx.x == 0) cnt = 0;
  __syncthreads();
  unsigned int v = w[(size_t)threadIdx.x * 1024];
  int e = (v >> 7) & 0xFF;
  bool ok = ((v & 0xFFFFu) == 0u) || (e > 100 && e < 150);
  if (ok) atomicAdd(&cnt, 1);
  __syncthreads();
  if (threadIdx.x == 0) *flag = (cnt >= 192) ? 1 : 0;
}

__global__ __launch_bounds__(256) void cvt_io(const void* __restrict__ pred, const void* __restrict__ refp,
                                              float* __restrict__ dst, const int* __restrict__ flag){
  int i = blockIdx.x*256 + threadIdx.x;
  bool bf = (*flag != 0);
  const int n = 9437184;
  const void* src = (i < n) ? pred : refp;
  int j = (i < n) ? i : i - n;
  dst[i] = ldmix(src, j, bf);
}

__global__ __launch_bounds__(256) void prep_w(const void* __restrict__ w1, const void* __restrict__ w2,
                                              const void* __restrict__ wr, const void* __restrict__ wp,
                                              const void* __restrict__ b1, const void* __restrict__ b2,
                                              const void* __restrict__ rb,
                                              float* __restrict__ w1f, float* __restrict__ w2f,
                                              float* __restrict__ wrf, float* __restrict__ wpf,
                                              float* __restrict__ b1f, float* __restrict__ b2f,
                                              float* __restrict__ rbf, const int* __restrict__ flag){
  int i = blockIdx.x*256 + threadIdx.x;
  bool bf = (*flag != 0);
  if (i < 36864){ int co = i & 63;  int t = i >> 6; int ci = t & 63; int tap = t >> 6;
    w1f[(tap*64+ci)*64+co]  = ldmix(w1, (co*64+ci)*9+tap, bf); }
  if (i < 73728){ int co = i & 127; int t = i >> 7; int ci = t & 63; int tap = t >> 6;
    w2f[(tap*64+ci)*128+co] = ldmix(w2, (co*64+ci)*9+tap, bf); }
  if (i < 4096){ int co = i & 31; int ci = i >> 5;
    wrf[ci*32+co] = ldmix(wr, co*128+ci, bf); }
  if (i < 8514){ int o = i & 1; int t = i >> 1; int c = t % 473; int tap = t / 473;
    wpf[tap*948 + c*2 + o] = ldmix(wp, (o*473+c)*9+tap, bf); }
  if (i < 64)  b1f[i] = ldmix(b1, i, bf);
  if (i < 128) b2f[i] = ldmix(b2, i, bf);
  if (i < 32)  rbf[i] = ldmix(rb, i, bf);
}

template<int CIN, int COUT, bool FP32_NCHW>
__global__ __launch_bounds__(256) void conv3x3_k(const void* __restrict__ in, const float* __restrict__ wf,
                                                 const float* __restrict__ bias, u16* __restrict__ out){
  constexpr int CB = COUT/64;
  __shared__ __align__(16) float s_in[8][18][20];
  __shared__ __align__(16) float s_w[9][8][64];
  int tid = threadIdx.x;
  int bx = blockIdx.x, by = blockIdx.y;
  int b8 = (int)blockIdx.z / CB, cob = (int)blockIdx.z % CB;
  int co0 = cob*64;
  size_t boff = (size_t)b8*HW*CIN;
  int ty = tid >> 4, cg = tid & 15;
  float4 acc[16];
  #pragma unroll
  for (int i=0;i<16;i++) acc[i] = make_float4(0.f,0.f,0.f,0.f);

  for (int ci0 = 0; ci0 < CIN; ci0 += 8){
    if (ci0) __syncthreads();
    for (int e = tid; e < 8*324; e += 256){
      int ci, r, c;
      if (FP32_NCHW){ ci = e / 324; int pp = e - ci*324; r = pp/18; c = pp - r*18; }
      else          { ci = e & 7;   int pp = e >> 3;     r = pp/18; c = pp - r*18; }
      int gy = by*16 + r - 1, gx = bx*16 + c - 1;
      float v = 0.f;
      if (gy >= 0 && gy < HH && gx >= 0 && gx < WW){
        if (FP32_NCHW) v = ((const float*)in)[boff + (size_t)(ci0+ci)*HW + (size_t)gy*WW + gx];
        else           v = b2f(((const u16*)in)[boff + ((size_t)gy*WW + gx)*CIN + ci0 + ci]);
      }
      s_in[ci][r][c] = v;
    }
    for (int e = tid; e < 9*8*64; e += 256){
      int co = e & 63; int t = e >> 6; int cl = t & 7; int tap = t >> 3;
      s_w[tap][cl][co] = wf[(size_t)(tap*CIN + ci0 + cl)*COUT + co0 + co];
    }
    __syncthreads();
    for (int cl = 0; cl < 8; ++cl){
      #pragma unroll
      for (int ky = 0; ky < 3; ++ky){
        const float* rp = &s_in[cl][ty+ky][0];
        float row[18];
        *(float4*)&row[0]  = *(const float4*)(rp);
        *(float4*)&row[4]  = *(const float4*)(rp+4);
        *(float4*)&row[8]  = *(const float4*)(rp+8);
        *(float4*)&row[12] = *(const float4*)(rp+12);
        *(float2*)&row[16] = *(const float2*)(rp+16);
        #pragma unroll
        for (int kx = 0; kx < 3; ++kx){
          float4 wv = *(const float4*)&s_w[ky*3+kx][cl][cg*4];
          #pragma unroll
          for (int px = 0; px < 16; ++px){
            float a = row[px+kx];
            acc[px].x += a*wv.x; acc[px].y += a*wv.y;
            acc[px].z += a*wv.z; acc[px].w += a*wv.w;
          }
        }
      }
    }
  }
  int gy = by*16 + ty;
  float bv0 = bias[co0+cg*4+0], bv1 = bias[co0+cg*4+1];
  float bv2 = bias[co0+cg*4+2], bv3 = bias[co0+cg*4+3];
  u16* op = out + ((size_t)b8*HW + (size_t)gy*WW + bx*16)*COUT + co0 + cg*4;
  #pragma unroll
  for (int px = 0; px < 16; ++px){
    float v0 = lrelu(acc[px].x + bv0);
    float v1 = lrelu(acc[px].y + bv1);
    float v2 = lrelu(acc[px].z + bv2);
    float v3 = lrelu(acc[px].w + bv3);
    uint2 pk;
    pk.x = (unsigned int)f2b(v0) | ((unsigned int)f2b(v1) << 16);
    pk.y = (unsigned int)f2b(v2) | ((unsigned int)f2b(v3) << 16);
    *(uint2*)(op + (size_t)px*COUT) = pk;
  }
}

// 1x1 redir conv (128->32) + bias + lrelu. X is NCHW [b][473][HW]; writes planes 0..31.
__global__ __launch_bounds__(256) void redir_k(const u16* __restrict__ C2, const float* __restrict__ wrf,
                                               const float* __restrict__ rbf, u16* __restrict__ X){
  int p = blockIdx.x*256 + threadIdx.x;
  int b = p / HW; int pix = p - b*HW;
  const u16* ap = C2 + (size_t)p*128;
  float acc[32];
  #pragma unroll
  for (int j=0;j<32;j++) acc[j]=0.f;
  for (int ci=0; ci<128; ci+=4){
    uint2 aw = *(const uint2*)(ap + ci);
    float a0,a1,a2,a3;
    up2(aw.x,a0,a1); up2(aw.y,a2,a3);
    const float* w0 = wrf + ci*32;
    #pragma unroll
    for (int co=0; co<32; co+=4){
      float4 wv0 = *(const float4*)(w0+co);
      float4 wv1 = *(const float4*)(w0+32+co);
      float4 wv2 = *(const float4*)(w0+64+co);
      float4 wv3 = *(const float4*)(w0+96+co);
      acc[co+0] += a0*wv0.x + a1*wv1.x + a2*wv2.x + a3*wv3.x;
      acc[co+1] += a0*wv0.y + a1*wv1.y + a2*wv2.y + a3*wv3.y;
      acc[co+2] += a0*wv0.z + a1*wv1.z + a2*wv2.z + a3*wv3.z;
      acc[co+3] += a0*wv0.w + a1*wv1.w + a2*wv2.w + a3*wv3.w;
    }
  }
  #pragma unroll
  for (int co=0; co<32; ++co){
    X[(size_t)(b*473 + co)*HW + pix] = f2b(lrelu(acc[co] + rbf[co]));
  }
}

// Correlation, NCHW output. Block = (y-pair, dy, b); 192 threads.
// Threads 0..95 -> row y0, 96..191 -> row y0+1. Each thread: pixels x, x+2
// (x = 4k+q) sharing every staged LDS position across its 21 dx accumulators.
// LDS: ref row segment as [row][ch8-group][pos] uint4 -> aligned, conflict-free
// ds_read_b128 (16B lane stride). 32-ch quarters bound VGPRs.
#define SEGP 233
__global__ __launch_bounds__(192) void corr_k(const u16* __restrict__ C2, u16* __restrict__ X){
  __shared__ __align__(16) uint4 s_seg[2][4][SEGP];
  int tid = threadIdx.x;
  int y0 = blockIdx.x*2;
  int dy = blockIdx.y;
  int b  = blockIdx.z;
  int row = (tid >= 96) ? 1 : 0;
  int p = tid - row*96;
  int q = p & 1, k = p >> 1;
  int x = 4*k + q;
  int y = y0 + row;
  int r0 = y0 + 2*dy - 20;
  const u16* predb = C2 + (size_t)b*HW*128;
  const u16* refb  = C2 + (size_t)(b+4)*HW*128;
  float acc0[21], acc1[21];
  #pragma unroll
  for (int i=0;i<21;i++){ acc0[i]=0.f; acc1[i]=0.f; }

  for (int quarter=0; quarter<4; ++quarter){
    int c0 = quarter*32;
    if (quarter) __syncthreads();
    // stage 2 ref rows x 232 pos x 32 ch (zeros for OOB rows/cols)
    for (int e = tid; e < 14848; e += 192){
      int rw = (e >= 7424) ? 1 : 0;
      int e2 = e - rw*7424;
      int pos = e2 >> 5, ch = e2 & 31;
      int rr = r0 + rw;
      int gx = pos - 20;
      u16 v = 0;
      if (rr >= 0 && rr < HH && gx >= 0 && gx < WW)
        v = refb[((size_t)rr*WW + gx)*128 + c0 + ch];
      ((u16*)s_seg)[(((rw*4 + (ch>>3))*SEGP + pos) << 3) + (ch & 7)] = v;
    }
    __syncthreads();
    // x1 fragments for the 2 pixels
    float av0[32], av1[32];
    const u16* a0p = predb + ((size_t)y*WW + x)*128 + c0;
    const u16* a1p = a0p + 2*128;
    #pragma unroll
    for (int i=0;i<4;i++){
      uint4 w = *(const uint4*)(a0p + i*8);
      up2(w.x, av0[i*8+0], av0[i*8+1]);
      up2(w.y, av0[i*8+2], av0[i*8+3]);
      up2(w.z, av0[i*8+4], av0[i*8+5]);
      up2(w.w, av0[i*8+6], av0[i*8+7]);
      uint4 u = *(const uint4*)(a1p + i*8);
      up2(u.x, av1[i*8+0], av1[i*8+1]);
      up2(u.y, av1[i*8+2], av1[i*8+3]);
      up2(u.z, av1[i*8+4], av1[i*8+5]);
      up2(u.w, av1[i*8+6], av1[i*8+7]);
    }
    // 22 staged positions feed acc0[0..20] (pixel x) and acc1[0..20] (pixel x+2)
    #pragma unroll
    for (int dxe = 0; dxe < 22; ++dxe){
      int pos = x + 2*dxe;
      uint4 w0 = s_seg[row][0][pos];
      uint4 w1 = s_seg[row][1][pos];
      uint4 w2 = s_seg[row][2][pos];
      uint4 w3 = s_seg[row][3][pos];
      float bv[32];
      up2(w0.x,bv[0],bv[1]);   up2(w0.y,bv[2],bv[3]);   up2(w0.z,bv[4],bv[5]);   up2(w0.w,bv[6],bv[7]);
      up2(w1.x,bv[8],bv[9]);   up2(w1.y,bv[10],bv[11]); up2(w1.z,bv[12],bv[13]); up2(w1.w,bv[14],bv[15]);
      up2(w2.x,bv[16],bv[17]); up2(w2.y,bv[18],bv[19]); up2(w2.z,bv[20],bv[21]); up2(w2.w,bv[22],bv[23]);
      up2(w3.x,bv[24],bv[25]); up2(w3.y,bv[26],bv[27]); up2(w3.z,bv[28],bv[29]); up2(w3.w,bv[30],bv[31]);
      if (dxe < 21){
        float s0=0.f,s1=0.f,s2=0.f,s3=0.f;
        #pragma unroll
        for (int j=0;j<8;j++){
          s0 += av0[j]*bv[j];       s1 += av0[8+j]*bv[8+j];
          s2 += av0[16+j]*bv[16+j]; s3 += av0[24+j]*bv[24+j];
        }
        acc0[dxe] += (s0+s1)+(s2+s3);
      }
      if (dxe > 0){
        float s0=0.f,s1=0.f,s2=0.f,s3=0.f;
        #pragma unroll
        for (int j=0;j<8;j++){
          s0 += av1[j]*bv[j];       s1 += av1[8+j]*bv[8+j];
          s2 += av1[16+j]*bv[16+j]; s3 += av1[24+j]*bv[24+j];
        }
        acc1[dxe-1] += (s0+s1)+(s2+s3);
      }
    }
  }
  // coalesced plane-row writes
  #pragma unroll
  for (int dx=0; dx<21; ++dx){
    u16* bp = X + ((size_t)(b*473 + 32 + dy*21 + dx)*HH + y)*WW;
    bp[x]   = f2b(lrelu(acc0[dx]*(1.f/128.f)));
    bp[x+2] = f2b(lrelu(acc1[dx]*(1.f/128.f)));
  }
}

// Final 3x3 conv over NCHW X (473 planes). Block = (y, b), 192 threads = x.
// Stages [3 rows][194 xp][8 ch] u16 per channel-chunk -> conflict-free b128.
__global__ __launch_bounds__(192) void final_k(const u16* __restrict__ X, const float* __restrict__ wpf,
                                               void* __restrict__ out, const int* __restrict__ flag){
  __shared__ __align__(16) u16 s_t[3][194][8];
  int x = threadIdx.x;
  int y = blockIdx.x;
  int b = blockIdx.y;
  float a0 = 0.f, a1 = 0.f;
  for (int c0 = 0; c0 < 473; c0 += 8){
    if (c0) __syncthreads();
    for (int e = x; e < 4656; e += 192){
      int ch = e & 7; int t = e >> 3; int xp = t % 194; int row = t / 194;
      int gy = y + row - 1, gx = xp - 1;
      int c = c0 + ch;
      u16 v = 0;
      if (c < 473 && gy >= 0 && gy < HH && gx >= 0 && gx < WW)
        v = X[((size_t)(b*473 + c)*HH + gy)*WW + gx];
      s_t[row][xp][ch] = v;
    }
    __syncthreads();
    #pragma unroll
    for (int ky = 0; ky < 3; ++ky){
      #pragma unroll
      for (int kx = 0; kx < 3; ++kx){
        uint4 w4 = *(const uint4*)&s_t[ky][x+kx][0];
        float v0,v1,v2,v3,v4,v5,v6,v7;
        up2(w4.x,v0,v1); up2(w4.y,v2,v3); up2(w4.z,v4,v5); up2(w4.w,v6,v7);
        const float* wt = wpf + (ky*3+kx)*948 + c0*2;   // lane-uniform -> s_load
        a0 += v0*wt[0]  + v1*wt[2]  + v2*wt[4]  + v3*wt[6]
            + v4*wt[8]  + v5*wt[10] + v6*wt[12] + v7*wt[14];
        a1 += v0*wt[1]  + v1*wt[3]  + v2*wt[5]  + v3*wt[7]
            + v4*wt[9]  + v5*wt[11] + v6*wt[13] + v7*wt[15];
      }
    }
  }
  size_t rem = (size_t)y*WW + x;
  size_t i0 = (size_t)(b*2)*HW + rem;
  size_t i1 = (size_t)(b*2+1)*HW + rem;
  if (*flag){
    ((u16*)out)[i0] = f2b(a0);
    ((u16*)out)[i1] = f2b(a1);
  } else {
    ((float*)out)[i0] = a0;
    ((float*)out)[i1] = a1;
  }
}

// Workspace (bytes):
//   [0, 75497472)          predf fp32 [8][64][HW] (dies after conv1); then C2 bf16 [8][HW][128]
//   [75497472, 113246208)  A: conv1 out bf16 [8][HW][64] (dies after conv2)
//   [75497472, 214964224)  X: NCHW bf16 [4][473][HW] (reuses A region)
//   [217055232, ...)       fp32 weights + biases + flag (~500 KB)
extern "C" void kernel_launch(void* const* d_in, const int* in_sizes, int n_in,
                              void* d_out, int out_size, void* d_ws, size_t ws_size,
                              hipStream_t stream){
  char* ws = (char*)d_ws;
  float* predf = (float*)ws;
  u16* C2 = (u16*)ws;
  u16* A  = (u16*)(ws + 75497472);
  u16* X  = (u16*)(ws + 75497472);
  float* w1f = (float*)(ws + 217055232);
  float* w2f = w1f + 9*64*64;
  float* wrf = w2f + 9*64*128;
  float* wpf = wrf + 128*32;
  float* b1f = wpf + 9*948 + 16;   // +16: final_k tail-chunk may read past 473*2 harmlessly
  float* b2f = b1f + 64;
  float* rbf = b2f + 128;
  int* flag  = (int*)(rbf + 32);

  detect_k<<<1,256,0,stream>>>((const unsigned int*)d_in[0], flag);
  cvt_io<<<73728,256,0,stream>>>(d_in[0], d_in[1], predf, flag);
  prep_w<<<288,256,0,stream>>>(d_in[2], d_in[4], d_in[6], d_in[8],
                               d_in[3], d_in[5], d_in[7],
                               w1f, w2f, wrf, wpf, b1f, b2f, rbf, flag);
  conv3x3_k<64,64,true  ><<<dim3(12,12,8), 256,0,stream>>>(predf, w1f, b1f, A);
  conv3x3_k<64,128,false><<<dim3(12,12,16),256,0,stream>>>(A, w2f, b2f, C2);
  redir_k<<<576,256,0,stream>>>(C2, wrf, rbf, X);
  corr_k<<<dim3(96,21,4),192,0,stream>>>(C2, X);
  final_k<<<dim3(192,4),192,0,stream>>>(X, wpf, d_out, flag);
}

// Round 5
// 1757.300 us; speedup vs baseline: 7.2912x; 6.9602x over previous
//
#include <hip/hip_runtime.h>
#include <hip/hip_bf16.h>

#define HH 192
#define WW 192
#define HW (HH*WW)

typedef unsigned short u16;

__device__ __forceinline__ float b2f(u16 u){
  union { unsigned int i; float f; } v; v.i = ((unsigned int)u) << 16; return v.f;
}
__device__ __forceinline__ u16 f2b(float f){
  union { unsigned int i; float f; } v; v.f = f;
  unsigned int r = v.i + 0x7FFFu + ((v.i >> 16) & 1u);
  return (u16)(r >> 16);
}
__device__ __forceinline__ void up2(unsigned int w, float& lo, float& hi){
  union { unsigned int i; float f; } a, b;
  a.i = w << 16; b.i = w & 0xFFFF0000u;
  lo = a.f; hi = b.f;
}
__device__ __forceinline__ float lrelu(float x){ return x >= 0.f ? x : 0.1f*x; }
__device__ __forceinline__ float ldmix(const void* p, int i, bool bf){
  return bf ? b2f(((const u16*)p)[i]) : ((const float*)p)[i];
}

// packed bf16x2 dot: d = a.l*b.l + a.h*b.h + c  (1 VALU op vs 3 for unpack+fma)
using bf2 = __attribute__((ext_vector_type(2))) __bf16;
__device__ __forceinline__ float dot2bf(unsigned int a, unsigned int b, float c){
#if __has_builtin(__builtin_amdgcn_fdot2_f32_bf16)
  union { unsigned int u; bf2 v; } ua, ub; ua.u = a; ub.u = b;
  return __builtin_amdgcn_fdot2_f32_bf16(ua.v, ub.v, c, false);
#else
  float al,ah,bl,bh; up2(a,al,ah); up2(b,bl,bh);
  return c + al*bl + ah*bh;
#endif
}

__global__ __launch_bounds__(256) void detect_k(const unsigned int* __restrict__ w, int* __restrict__ flag){
  __shared__ int cnt;
  if (threadIdx.x == 0) cnt = 0;
  __syncthreads();
  unsigned int v = w[(size_t)threadIdx.x * 1024];
  int e = (v >> 7) & 0xFF;
  bool ok = ((v & 0xFFFFu) == 0u) || (e > 100 && e < 150);
  if (ok) atomicAdd(&cnt, 1);
  __syncthreads();
  if (threadIdx.x == 0) *flag = (cnt >= 192) ? 1 : 0;
}

__global__ __launch_bounds__(256) void cvt_io(const void* __restrict__ pred, const void* __restrict__ refp,
                                              float* __restrict__ dst, const int* __restrict__ flag){
  int i = blockIdx.x*256 + threadIdx.x;
  bool bf = (*flag != 0);
  const int n = 9437184;
  const void* src = (i < n) ? pred : refp;
  int j = (i < n) ? i : i - n;
  dst[i] = ldmix(src, j, bf);
}

__global__ __launch_bounds__(256) void prep_w(const void* __restrict__ w1, const void* __restrict__ w2,
                                              const void* __restrict__ wr, const void* __restrict__ wp,
                                              const void* __restrict__ b1, const void* __restrict__ b2,
                                              const void* __restrict__ rb,
                                              float* __restrict__ w1f, float* __restrict__ w2f,
                                              float* __restrict__ wrf, float* __restrict__ wpf,
                                              float* __restrict__ b1f, float* __restrict__ b2f,
                                              float* __restrict__ rbf, const int* __restrict__ flag){
  int i = blockIdx.x*256 + threadIdx.x;
  bool bf = (*flag != 0);
  if (i < 36864){ int co = i & 63;  int t = i >> 6; int ci = t & 63; int tap = t >> 6;
    w1f[(tap*64+ci)*64+co]  = ldmix(w1, (co*64+ci)*9+tap, bf); }
  if (i < 73728){ int co = i & 127; int t = i >> 7; int ci = t & 63; int tap = t >> 6;
    w2f[(tap*64+ci)*128+co] = ldmix(w2, (co*64+ci)*9+tap, bf); }
  if (i < 4096){ int co = i & 31; int ci = i >> 5;
    wrf[ci*32+co] = ldmix(wr, co*128+ci, bf); }
  if (i < 8514){ int o = i & 1; int t = i >> 1; int c = t % 473; int tap = t / 473;
    wpf[tap*948 + c*2 + o] = ldmix(wp, (o*473+c)*9+tap, bf); }
  if (i < 64)  b1f[i] = ldmix(b1, i, bf);
  if (i < 128) b2f[i] = ldmix(b2, i, bf);
  if (i < 32)  rbf[i] = ldmix(rb, i, bf);
}

template<int CIN, int COUT, bool FP32_NCHW>
__global__ __launch_bounds__(256) void conv3x3_k(const void* __restrict__ in, const float* __restrict__ wf,
                                                 const float* __restrict__ bias, u16* __restrict__ out){
  constexpr int CB = COUT/64;
  __shared__ __align__(16) float s_in[8][18][20];
  __shared__ __align__(16) float s_w[9][8][64];
  int tid = threadIdx.x;
  int bx = blockIdx.x, by = blockIdx.y;
  int b8 = (int)blockIdx.z / CB, cob = (int)blockIdx.z % CB;
  int co0 = cob*64;
  size_t boff = (size_t)b8*HW*CIN;
  int ty = tid >> 4, cg = tid & 15;
  float4 acc[16];
  #pragma unroll
  for (int i=0;i<16;i++) acc[i] = make_float4(0.f,0.f,0.f,0.f);

  for (int ci0 = 0; ci0 < CIN; ci0 += 8){
    if (ci0) __syncthreads();
    for (int e = tid; e < 8*324; e += 256){
      int ci, r, c;
      if (FP32_NCHW){ ci = e / 324; int pp = e - ci*324; r = pp/18; c = pp - r*18; }
      else          { ci = e & 7;   int pp = e >> 3;     r = pp/18; c = pp - r*18; }
      int gy = by*16 + r - 1, gx = bx*16 + c - 1;
      float v = 0.f;
      if (gy >= 0 && gy < HH && gx >= 0 && gx < WW){
        if (FP32_NCHW) v = ((const float*)in)[boff + (size_t)(ci0+ci)*HW + (size_t)gy*WW + gx];
        else           v = b2f(((const u16*)in)[boff + ((size_t)gy*WW + gx)*CIN + ci0 + ci]);
      }
      s_in[ci][r][c] = v;
    }
    for (int e = tid; e < 9*8*64; e += 256){
      int co = e & 63; int t = e >> 6; int cl = t & 7; int tap = t >> 3;
      s_w[tap][cl][co] = wf[(size_t)(tap*CIN + ci0 + cl)*COUT + co0 + co];
    }
    __syncthreads();
    for (int cl = 0; cl < 8; ++cl){
      #pragma unroll
      for (int ky = 0; ky < 3; ++ky){
        const float* rp = &s_in[cl][ty+ky][0];
        float row[18];
        *(float4*)&row[0]  = *(const float4*)(rp);
        *(float4*)&row[4]  = *(const float4*)(rp+4);
        *(float4*)&row[8]  = *(const float4*)(rp+8);
        *(float4*)&row[12] = *(const float4*)(rp+12);
        *(float2*)&row[16] = *(const float2*)(rp+16);
        #pragma unroll
        for (int kx = 0; kx < 3; ++kx){
          float4 wv = *(const float4*)&s_w[ky*3+kx][cl][cg*4];
          #pragma unroll
          for (int px = 0; px < 16; ++px){
            float a = row[px+kx];
            acc[px].x += a*wv.x; acc[px].y += a*wv.y;
            acc[px].z += a*wv.z; acc[px].w += a*wv.w;
          }
        }
      }
    }
  }
  int gy = by*16 + ty;
  float bv0 = bias[co0+cg*4+0], bv1 = bias[co0+cg*4+1];
  float bv2 = bias[co0+cg*4+2], bv3 = bias[co0+cg*4+3];
  u16* op = out + ((size_t)b8*HW + (size_t)gy*WW + bx*16)*COUT + co0 + cg*4;
  #pragma unroll
  for (int px = 0; px < 16; ++px){
    float v0 = lrelu(acc[px].x + bv0);
    float v1 = lrelu(acc[px].y + bv1);
    float v2 = lrelu(acc[px].z + bv2);
    float v3 = lrelu(acc[px].w + bv3);
    uint2 pk;
    pk.x = (unsigned int)f2b(v0) | ((unsigned int)f2b(v1) << 16);
    pk.y = (unsigned int)f2b(v2) | ((unsigned int)f2b(v3) << 16);
    *(uint2*)(op + (size_t)px*COUT) = pk;
  }
}

// 1x1 redir conv (128->32) + bias + lrelu. X is NCHW [b][473][HW]; planes 0..31.
__global__ __launch_bounds__(256) void redir_k(const u16* __restrict__ C2, const float* __restrict__ wrf,
                                               const float* __restrict__ rbf, u16* __restrict__ X){
  int p = blockIdx.x*256 + threadIdx.x;
  int b = p / HW; int pix = p - b*HW;
  const u16* ap = C2 + (size_t)p*128;
  float acc[32];
  #pragma unroll
  for (int j=0;j<32;j++) acc[j]=0.f;
  for (int ci=0; ci<128; ci+=4){
    uint2 aw = *(const uint2*)(ap + ci);
    float a0,a1,a2,a3;
    up2(aw.x,a0,a1); up2(aw.y,a2,a3);
    const float* w0 = wrf + ci*32;
    #pragma unroll
    for (int co=0; co<32; co+=4){
      float4 wv0 = *(const float4*)(w0+co);
      float4 wv1 = *(const float4*)(w0+32+co);
      float4 wv2 = *(const float4*)(w0+64+co);
      float4 wv3 = *(const float4*)(w0+96+co);
      acc[co+0] += a0*wv0.x + a1*wv1.x + a2*wv2.x + a3*wv3.x;
      acc[co+1] += a0*wv0.y + a1*wv1.y + a2*wv2.y + a3*wv3.y;
      acc[co+2] += a0*wv0.z + a1*wv1.z + a2*wv2.z + a3*wv3.z;
      acc[co+3] += a0*wv0.w + a1*wv1.w + a2*wv2.w + a3*wv3.w;
    }
  }
  #pragma unroll
  for (int co=0; co<32; ++co){
    X[(size_t)(b*473 + co)*HW + pix] = f2b(lrelu(acc[co] + rbf[co]));
  }
}

// Correlation v3: thread = 1 pixel, block = 1 row, 16-ch chunks, packed bf16
// dot2. Live regs ~50 (acc[21]+av[8]+temps) -> no spills (round-4 root cause:
// VGPR=256 scratch spill traffic ~19.6 GB/dispatch).
#define SEGP 233
__global__ __launch_bounds__(192,4) void corr_k(const u16* __restrict__ C2, u16* __restrict__ X){
  __shared__ __align__(16) uint4 s_seg[2][SEGP];
  int x  = threadIdx.x;
  int y  = blockIdx.x;
  int dy = blockIdx.y;
  int b  = blockIdx.z;
  int r  = y + 2*dy - 20;
  u16* bp0 = X + ((size_t)(b*473 + 32 + dy*21)*HH + y)*WW;
  if (r < 0 || r >= HH){
    #pragma unroll
    for (int dx=0; dx<21; ++dx) bp0[(size_t)dx*HW + x] = 0;
    return;
  }
  const u16* arow = C2 + ((size_t)b*HW + (size_t)y*WW + x)*128;
  const u16* brow = C2 + ((size_t)(b+4)*HW + (size_t)r*WW)*128;
  float acc[21];
  #pragma unroll
  for (int i=0;i<21;i++) acc[i]=0.f;

  for (int c0 = 0; c0 < 128; c0 += 16){
    if (c0) __syncthreads();
    // stage ref row positions [-20, 212) x 16 ch as two 8-ch uint4 groups
    for (int e = x; e < 464; e += 192){
      int g = e & 1, pos = e >> 1;
      int gx = pos - 20;
      uint4 v = make_uint4(0,0,0,0);
      if (gx >= 0 && gx < WW) v = *(const uint4*)(brow + (size_t)gx*128 + c0 + g*8);
      s_seg[g][pos] = v;
    }
    __syncthreads();
    unsigned int av[8];
    *(uint4*)&av[0] = *(const uint4*)(arow + c0);
    *(uint4*)&av[4] = *(const uint4*)(arow + c0 + 8);
    #pragma unroll
    for (int dx = 0; dx < 21; ++dx){
      int pos = x + 2*dx;
      uint4 b0 = s_seg[0][pos];
      uint4 b1 = s_seg[1][pos];
      float a = acc[dx];
      a = dot2bf(av[0], b0.x, a);
      a = dot2bf(av[1], b0.y, a);
      a = dot2bf(av[2], b0.z, a);
      a = dot2bf(av[3], b0.w, a);
      a = dot2bf(av[4], b1.x, a);
      a = dot2bf(av[5], b1.y, a);
      a = dot2bf(av[6], b1.z, a);
      a = dot2bf(av[7], b1.w, a);
      acc[dx] = a;
    }
  }
  #pragma unroll
  for (int dx=0; dx<21; ++dx)
    bp0[(size_t)dx*HW + x] = f2b(lrelu(acc[dx]*(1.f/128.f)));
}

// Final 3x3 conv over NCHW X (473 planes). Block = (y, b), 192 threads = x.
__global__ __launch_bounds__(192) void final_k(const u16* __restrict__ X, const float* __restrict__ wpf,
                                               void* __restrict__ out, const int* __restrict__ flag){
  __shared__ __align__(16) u16 s_t[3][194][8];
  int x = threadIdx.x;
  int y = blockIdx.x;
  int b = blockIdx.y;
  float a0 = 0.f, a1 = 0.f;
  for (int c0 = 0; c0 < 473; c0 += 8){
    if (c0) __syncthreads();
    for (int e = x; e < 4656; e += 192){
      int ch = e & 7; int t = e >> 3; int xp = t % 194; int row = t / 194;
      int gy = y + row - 1, gx = xp - 1;
      int c = c0 + ch;
      u16 v = 0;
      if (c < 473 && gy >= 0 && gy < HH && gx >= 0 && gx < WW)
        v = X[((size_t)(b*473 + c)*HH + gy)*WW + gx];
      s_t[row][xp][ch] = v;
    }
    __syncthreads();
    #pragma unroll
    for (int ky = 0; ky < 3; ++ky){
      #pragma unroll
      for (int kx = 0; kx < 3; ++kx){
        uint4 w4 = *(const uint4*)&s_t[ky][x+kx][0];
        float v0,v1,v2,v3,v4,v5,v6,v7;
        up2(w4.x,v0,v1); up2(w4.y,v2,v3); up2(w4.z,v4,v5); up2(w4.w,v6,v7);
        const float* wt = wpf + (ky*3+kx)*948 + c0*2;
        a0 += v0*wt[0]  + v1*wt[2]  + v2*wt[4]  + v3*wt[6]
            + v4*wt[8]  + v5*wt[10] + v6*wt[12] + v7*wt[14];
        a1 += v0*wt[1]  + v1*wt[3]  + v2*wt[5]  + v3*wt[7]
            + v4*wt[9]  + v5*wt[11] + v6*wt[13] + v7*wt[15];
      }
    }
  }
  size_t rem = (size_t)y*WW + x;
  size_t i0 = (size_t)(b*2)*HW + rem;
  size_t i1 = (size_t)(b*2+1)*HW + rem;
  if (*flag){
    ((u16*)out)[i0] = f2b(a0);
    ((u16*)out)[i1] = f2b(a1);
  } else {
    ((float*)out)[i0] = a0;
    ((float*)out)[i1] = a1;
  }
}

// Workspace (bytes):
//   [0, 75497472)          predf fp32 [8][64][HW] (dies after conv1); then C2 bf16 [8][HW][128]
//   [75497472, 113246208)  A: conv1 out bf16 [8][HW][64] (dies after conv2)
//   [75497472, 214964224)  X: NCHW bf16 [4][473][HW] (reuses A region)
//   [217055232, ...)       fp32 weights + biases + flag (~500 KB)
extern "C" void kernel_launch(void* const* d_in, const int* in_sizes, int n_in,
                              void* d_out, int out_size, void* d_ws, size_t ws_size,
                              hipStream_t stream){
  char* ws = (char*)d_ws;
  float* predf = (float*)ws;
  u16* C2 = (u16*)ws;
  u16* A  = (u16*)(ws + 75497472);
  u16* X  = (u16*)(ws + 75497472);
  float* w1f = (float*)(ws + 217055232);
  float* w2f = w1f + 9*64*64;
  float* wrf = w2f + 9*64*128;
  float* wpf = wrf + 128*32;
  float* b1f = wpf + 9*948 + 16;
  float* b2f = b1f + 64;
  float* rbf = b2f + 128;
  int* flag  = (int*)(rbf + 32);

  detect_k<<<1,256,0,stream>>>((const unsigned int*)d_in[0], flag);
  cvt_io<<<73728,256,0,stream>>>(d_in[0], d_in[1], predf, flag);
  prep_w<<<288,256,0,stream>>>(d_in[2], d_in[4], d_in[6], d_in[8],
                               d_in[3], d_in[5], d_in[7],
                               w1f, w2f, wrf, wpf, b1f, b2f, rbf, flag);
  conv3x3_k<64,64,true  ><<<dim3(12,12,8), 256,0,stream>>>(predf, w1f, b1f, A);
  conv3x3_k<64,128,false><<<dim3(12,12,16),256,0,stream>>>(A, w2f, b2f, C2);
  redir_k<<<576,256,0,stream>>>(C2, wrf, rbf, X);
  corr_k<<<dim3(192,21,4),192,0,stream>>>(C2, X);
  final_k<<<dim3(192,4),192,0,stream>>>(X, wpf, d_out, flag);
}

// Round 6
// 1440.755 us; speedup vs baseline: 8.8931x; 1.2197x over previous
//
#include <hip/hip_runtime.h>
#include <hip/hip_bf16.h>

#define HH 192
#define WW 192
#define HW (HH*WW)

typedef unsigned short u16;

__device__ __forceinline__ float b2f(u16 u){
  union { unsigned int i; float f; } v; v.i = ((unsigned int)u) << 16; return v.f;
}
__device__ __forceinline__ u16 f2b(float f){
  union { unsigned int i; float f; } v; v.f = f;
  unsigned int r = v.i + 0x7FFFu + ((v.i >> 16) & 1u);
  return (u16)(r >> 16);
}
__device__ __forceinline__ void up2(unsigned int w, float& lo, float& hi){
  union { unsigned int i; float f; } a, b;
  a.i = w << 16; b.i = w & 0xFFFF0000u;
  lo = a.f; hi = b.f;
}
__device__ __forceinline__ float lrelu(float x){ return x >= 0.f ? x : 0.1f*x; }
__device__ __forceinline__ float ldmix(const void* p, int i, bool bf){
  return bf ? b2f(((const u16*)p)[i]) : ((const float*)p)[i];
}

// packed bf16x2 dot: d = a.l*b.l + a.h*b.h + c
using bf2 = __attribute__((ext_vector_type(2))) __bf16;
__device__ __forceinline__ float dot2bf(unsigned int a, unsigned int b, float c){
#if __has_builtin(__builtin_amdgcn_fdot2_f32_bf16)
  union { unsigned int u; bf2 v; } ua, ub; ua.u = a; ub.u = b;
  return __builtin_amdgcn_fdot2_f32_bf16(ua.v, ub.v, c, false);
#else
  float al,ah,bl,bh; up2(a,al,ah); up2(b,bl,bh);
  return c + al*bl + ah*bh;
#endif
}

__global__ __launch_bounds__(256) void detect_k(const unsigned int* __restrict__ w, int* __restrict__ flag){
  __shared__ int cnt;
  if (threadIdx.x == 0) cnt = 0;
  __syncthreads();
  unsigned int v = w[(size_t)threadIdx.x * 1024];
  int e = (v >> 7) & 0xFF;
  bool ok = ((v & 0xFFFFu) == 0u) || (e > 100 && e < 150);
  if (ok) atomicAdd(&cnt, 1);
  __syncthreads();
  if (threadIdx.x == 0) *flag = (cnt >= 192) ? 1 : 0;
}

__global__ __launch_bounds__(256) void cvt_io(const void* __restrict__ pred, const void* __restrict__ refp,
                                              float* __restrict__ dst, const int* __restrict__ flag){
  int i = blockIdx.x*256 + threadIdx.x;
  bool bf = (*flag != 0);
  const int n = 9437184;
  const void* src = (i < n) ? pred : refp;
  int j = (i < n) ? i : i - n;
  dst[i] = ldmix(src, j, bf);
}

__global__ __launch_bounds__(256) void prep_w(const void* __restrict__ w1, const void* __restrict__ w2,
                                              const void* __restrict__ wr, const void* __restrict__ wp,
                                              const void* __restrict__ b1, const void* __restrict__ b2,
                                              const void* __restrict__ rb,
                                              float* __restrict__ w1f, float* __restrict__ w2f,
                                              float* __restrict__ wrf, unsigned int* __restrict__ wpb,
                                              float* __restrict__ b1f, float* __restrict__ b2f,
                                              float* __restrict__ rbf, const int* __restrict__ flag){
  int i = blockIdx.x*256 + threadIdx.x;
  bool bf = (*flag != 0);
  if (i < 36864){ int co = i & 63;  int t = i >> 6; int ci = t & 63; int tap = t >> 6;
    w1f[(tap*64+ci)*64+co]  = ldmix(w1, (co*64+ci)*9+tap, bf); }
  if (i < 73728){ int co = i & 127; int t = i >> 7; int ci = t & 63; int tap = t >> 6;
    w2f[(tap*64+ci)*128+co] = ldmix(w2, (co*64+ci)*9+tap, bf); }
  if (i < 4096){ int co = i & 31; int ci = i >> 5;
    wrf[ci*32+co] = ldmix(wr, co*128+ci, bf); }
  // final-conv weights: packed bf16 channel-pairs. wpb[cp*18 + tap*2 + o] =
  // pack(w[o][2cp][tap], w[o][2cp+1][tap]); c=473.. padded with 0.
  if (i < 4266){
    int cp = i/18; int rr = i - cp*18; int tap = rr >> 1; int o = rr & 1;
    int c0 = 2*cp, c1 = c0 + 1;
    float f0 = ldmix(wp, (o*473+c0)*9+tap, bf);
    float f1 = (c1 < 473) ? ldmix(wp, (o*473+c1)*9+tap, bf) : 0.f;
    wpb[i] = (unsigned int)f2b(f0) | ((unsigned int)f2b(f1) << 16);
  }
  if (i < 64)  b1f[i] = ldmix(b1, i, bf);
  if (i < 128) b2f[i] = ldmix(b2, i, bf);
  if (i < 32)  rbf[i] = ldmix(rb, i, bf);
}

template<int CIN, int COUT, bool FP32_NCHW>
__global__ __launch_bounds__(256) void conv3x3_k(const void* __restrict__ in, const float* __restrict__ wf,
                                                 const float* __restrict__ bias, u16* __restrict__ out){
  constexpr int CB = COUT/64;
  __shared__ __align__(16) float s_in[8][18][20];
  __shared__ __align__(16) float s_w[9][8][64];
  int tid = threadIdx.x;
  int bx = blockIdx.x, by = blockIdx.y;
  int b8 = (int)blockIdx.z / CB, cob = (int)blockIdx.z % CB;
  int co0 = cob*64;
  size_t boff = (size_t)b8*HW*CIN;
  int ty = tid >> 4, cg = tid & 15;
  float4 acc[16];
  #pragma unroll
  for (int i=0;i<16;i++) acc[i] = make_float4(0.f,0.f,0.f,0.f);

  for (int ci0 = 0; ci0 < CIN; ci0 += 8){
    if (ci0) __syncthreads();
    for (int e = tid; e < 8*324; e += 256){
      int ci, r, c;
      if (FP32_NCHW){ ci = e / 324; int pp = e - ci*324; r = pp/18; c = pp - r*18; }
      else          { ci = e & 7;   int pp = e >> 3;     r = pp/18; c = pp - r*18; }
      int gy = by*16 + r - 1, gx = bx*16 + c - 1;
      float v = 0.f;
      if (gy >= 0 && gy < HH && gx >= 0 && gx < WW){
        if (FP32_NCHW) v = ((const float*)in)[boff + (size_t)(ci0+ci)*HW + (size_t)gy*WW + gx];
        else           v = b2f(((const u16*)in)[boff + ((size_t)gy*WW + gx)*CIN + ci0 + ci]);
      }
      s_in[ci][r][c] = v;
    }
    for (int e = tid; e < 9*8*64; e += 256){
      int co = e & 63; int t = e >> 6; int cl = t & 7; int tap = t >> 3;
      s_w[tap][cl][co] = wf[(size_t)(tap*CIN + ci0 + cl)*COUT + co0 + co];
    }
    __syncthreads();
    for (int cl = 0; cl < 8; ++cl){
      #pragma unroll
      for (int ky = 0; ky < 3; ++ky){
        const float* rp = &s_in[cl][ty+ky][0];
        float row[18];
        *(float4*)&row[0]  = *(const float4*)(rp);
        *(float4*)&row[4]  = *(const float4*)(rp+4);
        *(float4*)&row[8]  = *(const float4*)(rp+8);
        *(float4*)&row[12] = *(const float4*)(rp+12);
        *(float2*)&row[16] = *(const float2*)(rp+16);
        #pragma unroll
        for (int kx = 0; kx < 3; ++kx){
          float4 wv = *(const float4*)&s_w[ky*3+kx][cl][cg*4];
          #pragma unroll
          for (int px = 0; px < 16; ++px){
            float a = row[px+kx];
            acc[px].x += a*wv.x; acc[px].y += a*wv.y;
            acc[px].z += a*wv.z; acc[px].w += a*wv.w;
          }
        }
      }
    }
  }
  int gy = by*16 + ty;
  float bv0 = bias[co0+cg*4+0], bv1 = bias[co0+cg*4+1];
  float bv2 = bias[co0+cg*4+2], bv3 = bias[co0+cg*4+3];
  u16* op = out + ((size_t)b8*HW + (size_t)gy*WW + bx*16)*COUT + co0 + cg*4;
  #pragma unroll
  for (int px = 0; px < 16; ++px){
    float v0 = lrelu(acc[px].x + bv0);
    float v1 = lrelu(acc[px].y + bv1);
    float v2 = lrelu(acc[px].z + bv2);
    float v3 = lrelu(acc[px].w + bv3);
    uint2 pk;
    pk.x = (unsigned int)f2b(v0) | ((unsigned int)f2b(v1) << 16);
    pk.y = (unsigned int)f2b(v2) | ((unsigned int)f2b(v3) << 16);
    *(uint2*)(op + (size_t)px*COUT) = pk;
  }
}

// 1x1 redir conv (128->32) + bias + lrelu. X is NCHW [b][473][HW]; planes 0..31.
__global__ __launch_bounds__(256) void redir_k(const u16* __restrict__ C2, const float* __restrict__ wrf,
                                               const float* __restrict__ rbf, u16* __restrict__ X){
  int p = blockIdx.x*256 + threadIdx.x;
  int b = p / HW; int pix = p - b*HW;
  const u16* ap = C2 + (size_t)p*128;
  float acc[32];
  #pragma unroll
  for (int j=0;j<32;j++) acc[j]=0.f;
  for (int ci=0; ci<128; ci+=4){
    uint2 aw = *(const uint2*)(ap + ci);
    float a0,a1,a2,a3;
    up2(aw.x,a0,a1); up2(aw.y,a2,a3);
    const float* w0 = wrf + ci*32;
    #pragma unroll
    for (int co=0; co<32; co+=4){
      float4 wv0 = *(const float4*)(w0+co);
      float4 wv1 = *(const float4*)(w0+32+co);
      float4 wv2 = *(const float4*)(w0+64+co);
      float4 wv3 = *(const float4*)(w0+96+co);
      acc[co+0] += a0*wv0.x + a1*wv1.x + a2*wv2.x + a3*wv3.x;
      acc[co+1] += a0*wv0.y + a1*wv1.y + a2*wv2.y + a3*wv3.y;
      acc[co+2] += a0*wv0.z + a1*wv1.z + a2*wv2.z + a3*wv3.z;
      acc[co+3] += a0*wv0.w + a1*wv1.w + a2*wv2.w + a3*wv3.w;
    }
  }
  #pragma unroll
  for (int co=0; co<32; ++co){
    X[(size_t)(b*473 + co)*HW + pix] = f2b(lrelu(acc[co] + rbf[co]));
  }
}

// Correlation: thread = 1 pixel, block = 1 row, 16-ch chunks, packed bf16 dot2.
#define SEGP 233
__global__ __launch_bounds__(192,4) void corr_k(const u16* __restrict__ C2, u16* __restrict__ X){
  __shared__ __align__(16) uint4 s_seg[2][SEGP];
  int x  = threadIdx.x;
  int y  = blockIdx.x;
  int dy = blockIdx.y;
  int b  = blockIdx.z;
  int r  = y + 2*dy - 20;
  u16* bp0 = X + ((size_t)(b*473 + 32 + dy*21)*HH + y)*WW;
  if (r < 0 || r >= HH){
    #pragma unroll
    for (int dx=0; dx<21; ++dx) bp0[(size_t)dx*HW + x] = 0;
    return;
  }
  const u16* arow = C2 + ((size_t)b*HW + (size_t)y*WW + x)*128;
  const u16* brow = C2 + ((size_t)(b+4)*HW + (size_t)r*WW)*128;
  float acc[21];
  #pragma unroll
  for (int i=0;i<21;i++) acc[i]=0.f;

  for (int c0 = 0; c0 < 128; c0 += 16){
    if (c0) __syncthreads();
    for (int e = x; e < 464; e += 192){
      int g = e & 1, pos = e >> 1;
      int gx = pos - 20;
      uint4 v = make_uint4(0,0,0,0);
      if (gx >= 0 && gx < WW) v = *(const uint4*)(brow + (size_t)gx*128 + c0 + g*8);
      s_seg[g][pos] = v;
    }
    __syncthreads();
    unsigned int av[8];
    *(uint4*)&av[0] = *(const uint4*)(arow + c0);
    *(uint4*)&av[4] = *(const uint4*)(arow + c0 + 8);
    #pragma unroll
    for (int dx = 0; dx < 21; ++dx){
      int pos = x + 2*dx;
      uint4 b0 = s_seg[0][pos];
      uint4 b1 = s_seg[1][pos];
      float a = acc[dx];
      a = dot2bf(av[0], b0.x, a);
      a = dot2bf(av[1], b0.y, a);
      a = dot2bf(av[2], b0.z, a);
      a = dot2bf(av[3], b0.w, a);
      a = dot2bf(av[4], b1.x, a);
      a = dot2bf(av[5], b1.y, a);
      a = dot2bf(av[6], b1.z, a);
      a = dot2bf(av[7], b1.w, a);
      acc[dx] = a;
    }
  }
  #pragma unroll
  for (int dx=0; dx<21; ++dx)
    bp0[(size_t)dx*HW + x] = f2b(lrelu(acc[dx]*(1.f/128.f)));
}

// Final 3x3 conv v2: contribution-passing, no staging. Thread = pixel, block =
// row (192 thr = 3 waves). Each thread reads only its own column (coalesced
// u16 loads), packs channel-pairs, accumulates P_mid/P_left/P_right via dot2,
// then one shuffle + tiny LDS wave-edge exchange combines neighbors.
__global__ __launch_bounds__(192) void final_k(const u16* __restrict__ X, const unsigned int* __restrict__ wpb,
                                               void* __restrict__ out, const int* __restrict__ flag){
  __shared__ float eR[4][2], eL[4][2];
  int x = threadIdx.x, y = blockIdx.x, b = blockIdx.y;
  int w = x >> 6, lane = x & 63;
  const u16* Xb = X + (size_t)b*473*HW;
  float Pm0=0.f,Pm1=0.f,Pl0=0.f,Pl1=0.f,Pr0=0.f,Pr1=0.f;
  bool rok0 = (y > 0), rok2 = (y < HH-1);
  size_t off0 = (size_t)(y-1)*WW + x;
  size_t off1 = (size_t)(y  )*WW + x;
  size_t off2 = (size_t)(y+1)*WW + x;

  for (int cp = 0; cp < 237; ++cp){
    const unsigned int* w18 = wpb + cp*18;
    size_t base0 = (size_t)(2*cp)*HW;
    size_t base1 = base0 + HW;
    bool c1ok = (2*cp+1) < 473;
    #pragma unroll
    for (int r = 0; r < 3; ++r){
      bool ok = (r==0) ? rok0 : ((r==2) ? rok2 : true);
      size_t off = (r==0) ? off0 : ((r==2) ? off2 : off1);
      unsigned int v = 0;
      if (ok){
        unsigned int lo = Xb[base0 + off];
        unsigned int hi = c1ok ? (unsigned int)Xb[base1 + off] : 0u;
        v = lo | (hi << 16);
      }
      // value(row r=ky) -> P_mid: kx=1; P_left(out x-1): kx=2; P_right(out x+1): kx=0
      Pm0 = dot2bf(v, w18[(r*3+1)*2+0], Pm0);
      Pm1 = dot2bf(v, w18[(r*3+1)*2+1], Pm1);
      Pl0 = dot2bf(v, w18[(r*3+2)*2+0], Pl0);
      Pl1 = dot2bf(v, w18[(r*3+2)*2+1], Pl1);
      Pr0 = dot2bf(v, w18[(r*3+0)*2+0], Pr0);
      Pr1 = dot2bf(v, w18[(r*3+0)*2+1], Pr1);
    }
  }

  // combine: out(x) = Pm(x) + Pr(x-1) + Pl(x+1)
  float r0 = __shfl_up(Pr0,1), r1 = __shfl_up(Pr1,1);
  float l0 = __shfl_down(Pl0,1), l1 = __shfl_down(Pl1,1);
  if (x == 0){ eR[0][0]=0.f; eR[0][1]=0.f; eL[3][0]=0.f; eL[3][1]=0.f; }
  if (lane == 63){ eR[w+1][0]=Pr0; eR[w+1][1]=Pr1; }
  if (lane == 0 && w > 0){ eL[w][0]=Pl0; eL[w][1]=Pl1; }
  __syncthreads();
  if (lane == 0){ r0 = eR[w][0]; r1 = eR[w][1]; }
  if (lane == 63){ l0 = eL[w+1][0]; l1 = eL[w+1][1]; }
  float a0 = Pm0 + r0 + l0;
  float a1 = Pm1 + r1 + l1;

  size_t rem = (size_t)y*WW + x;
  size_t i0 = (size_t)(b*2)*HW + rem;
  size_t i1 = (size_t)(b*2+1)*HW + rem;
  if (*flag){
    ((u16*)out)[i0] = f2b(a0);
    ((u16*)out)[i1] = f2b(a1);
  } else {
    ((float*)out)[i0] = a0;
    ((float*)out)[i1] = a1;
  }
}

// Workspace (bytes):
//   [0, 75497472)          predf fp32 [8][64][HW] (dies after conv1); then C2 bf16 [8][HW][128]
//   [75497472, 113246208)  A: conv1 out bf16 [8][HW][64] (dies after conv2)
//   [75497472, 214964224)  X: NCHW bf16 [4][473][HW] (reuses A region)
//   [217055232, ...)       fp32 weights + packed final weights + biases + flag
extern "C" void kernel_launch(void* const* d_in, const int* in_sizes, int n_in,
                              void* d_out, int out_size, void* d_ws, size_t ws_size,
                              hipStream_t stream){
  char* ws = (char*)d_ws;
  float* predf = (float*)ws;
  u16* C2 = (u16*)ws;
  u16* A  = (u16*)(ws + 75497472);
  u16* X  = (u16*)(ws + 75497472);
  float* w1f = (float*)(ws + 217055232);
  float* w2f = w1f + 9*64*64;
  float* wrf = w2f + 9*64*128;
  unsigned int* wpb = (unsigned int*)(wrf + 128*32);
  float* b1f = (float*)(wpb + 4266);
  float* b2f = b1f + 64;
  float* rbf = b2f + 128;
  int* flag  = (int*)(rbf + 32);

  detect_k<<<1,256,0,stream>>>((const unsigned int*)d_in[0], flag);
  cvt_io<<<73728,256,0,stream>>>(d_in[0], d_in[1], predf, flag);
  prep_w<<<288,256,0,stream>>>(d_in[2], d_in[4], d_in[6], d_in[8],
                               d_in[3], d_in[5], d_in[7],
                               w1f, w2f, wrf, wpb, b1f, b2f, rbf, flag);
  conv3x3_k<64,64,true  ><<<dim3(12,12,8), 256,0,stream>>>(predf, w1f, b1f, A);
  conv3x3_k<64,128,false><<<dim3(12,12,16),256,0,stream>>>(A, w2f, b2f, C2);
  redir_k<<<576,256,0,stream>>>(C2, wrf, rbf, X);
  corr_k<<<dim3(192,21,4),192,0,stream>>>(C2, X);
  final_k<<<dim3(192,4),192,0,stream>>>(X, wpb, d_out, flag);
}

// Round 7
// 809.798 us; speedup vs baseline: 15.8222x; 1.7792x over previous
//
#include <hip/hip_runtime.h>
#include <hip/hip_bf16.h>

#define HH 192
#define WW 192
#define HW (HH*WW)

typedef unsigned short u16;
typedef __attribute__((ext_vector_type(8))) short short8;
typedef __attribute__((ext_vector_type(16))) float float16;

__device__ __forceinline__ float b2f(u16 u){
  union { unsigned int i; float f; } v; v.i = ((unsigned int)u) << 16; return v.f;
}
__device__ __forceinline__ u16 f2b(float f){
  union { unsigned int i; float f; } v; v.f = f;
  unsigned int r = v.i + 0x7FFFu + ((v.i >> 16) & 1u);
  return (u16)(r >> 16);
}
__device__ __forceinline__ void up2(unsigned int w, float& lo, float& hi){
  union { unsigned int i; float f; } a, b;
  a.i = w << 16; b.i = w & 0xFFFF0000u;
  lo = a.f; hi = b.f;
}
__device__ __forceinline__ float lrelu(float x){ return x >= 0.f ? x : 0.1f*x; }
__device__ __forceinline__ float ldmix(const void* p, int i, bool bf){
  return bf ? b2f(((const u16*)p)[i]) : ((const float*)p)[i];
}

using bf2 = __attribute__((ext_vector_type(2))) __bf16;
__device__ __forceinline__ float dot2bf(unsigned int a, unsigned int b, float c){
#if __has_builtin(__builtin_amdgcn_fdot2_f32_bf16)
  union { unsigned int u; bf2 v; } ua, ub; ua.u = a; ub.u = b;
  return __builtin_amdgcn_fdot2_f32_bf16(ua.v, ub.v, c, false);
#else
  float al,ah,bl,bh; up2(a,al,ah); up2(b,bl,bh);
  return c + al*bl + ah*bh;
#endif
}

__global__ __launch_bounds__(256) void detect_k(const unsigned int* __restrict__ w, int* __restrict__ flag){
  __shared__ int cnt;
  if (threadIdx.x == 0) cnt = 0;
  __syncthreads();
  unsigned int v = w[(size_t)threadIdx.x * 1024];
  int e = (v >> 7) & 0xFF;
  bool ok = ((v & 0xFFFFu) == 0u) || (e > 100 && e < 150);
  if (ok) atomicAdd(&cnt, 1);
  __syncthreads();
  if (threadIdx.x == 0) *flag = (cnt >= 192) ? 1 : 0;
}

// NCHW (fp32 or bf16) -> NHWC bf16 [8][HW][64] via LDS transpose tile.
__global__ __launch_bounds__(256) void cvt_t(const void* __restrict__ pred, const void* __restrict__ refp,
                                             u16* __restrict__ X1, const int* __restrict__ flag){
  __shared__ u16 t[64*72];
  int tid = threadIdx.x;
  int px0 = blockIdx.x*64, img = blockIdx.y;
  bool bf = (*flag != 0);
  const void* src = (img < 4) ? pred : refp;
  int im = (img < 4) ? img : img - 4;
  for (int e = tid; e < 4096; e += 256){
    int ch = e >> 6, px = e & 63;
    t[px*72 + ch] = f2b(ldmix(src, (im*64 + ch)*HW + px0 + px, bf));
  }
  __syncthreads();
  int px = tid >> 2, q = tid & 3;
  uint4 v0 = *(const uint4*)(t + px*72 + q*16);
  uint4 v1 = *(const uint4*)(t + px*72 + q*16 + 8);
  u16* dst = X1 + ((size_t)img*HW + px0 + px)*64 + q*16;
  *(uint4*)dst = v0;
  *(uint4*)(dst + 8) = v1;
}

// Weight prep:
//  w1m/w2m: bf16 in MFMA A-frag lane order: [tap][ks][cotile][lane][8],
//           elem = W[co=cot*32+(lane&31)][ci=ks*16+(lane>>5)*8+j][tap]
//  wrf: fp32 [ci][co] (redir); wpb: packed bf16 pairs (final); biases fp32.
__global__ __launch_bounds__(256) void prep_w(const void* __restrict__ w1, const void* __restrict__ w2,
                                              const void* __restrict__ wr, const void* __restrict__ wp,
                                              const void* __restrict__ b1, const void* __restrict__ b2,
                                              const void* __restrict__ rb,
                                              u16* __restrict__ w1m, u16* __restrict__ w2m,
                                              float* __restrict__ wrf, unsigned int* __restrict__ wpb,
                                              float* __restrict__ b1f, float* __restrict__ b2f,
                                              float* __restrict__ rbf, const int* __restrict__ flag){
  int i = blockIdx.x*256 + threadIdx.x;
  bool bf = (*flag != 0);
  if (i < 36864){
    int j = i & 7, lane = (i>>3) & 63, cot = (i>>9) & 1, ks = (i>>10) & 3, tap = i >> 12;
    int co = cot*32 + (lane & 31), ci = ks*16 + (lane>>5)*8 + j;
    w1m[i] = f2b(ldmix(w1, (co*64 + ci)*9 + tap, bf));
  }
  if (i < 73728){
    int j = i & 7, lane = (i>>3) & 63, cot = (i>>9) & 3, ks = (i>>11) & 3, tap = i >> 13;
    int co = cot*32 + (lane & 31), ci = ks*16 + (lane>>5)*8 + j;
    w2m[i] = f2b(ldmix(w2, (co*64 + ci)*9 + tap, bf));
  }
  if (i < 4096){ int co = i & 31; int ci = i >> 5;
    wrf[ci*32+co] = ldmix(wr, co*128+ci, bf); }
  if (i < 4266){
    int cp = i/18; int rr = i - cp*18; int tap = rr >> 1; int o = rr & 1;
    int c0 = 2*cp, c1 = c0 + 1;
    float f0 = ldmix(wp, (o*473+c0)*9+tap, bf);
    float f1 = (c1 < 473) ? ldmix(wp, (o*473+c1)*9+tap, bf) : 0.f;
    wpb[i] = (unsigned int)f2b(f0) | ((unsigned int)f2b(f1) << 16);
  }
  if (i < 64)  b1f[i] = ldmix(b1, i, bf);
  if (i < 128) b2f[i] = ldmix(b2, i, bf);
  if (i < 32)  rbf[i] = ldmix(rb, i, bf);
}

// MFMA implicit-GEMM 3x3 conv, pad=1, NHWC bf16 in/out, bias+lrelu.
// Block: 128 px (4 rows x 32 x) x COUT (=WCO*64). Wave: 64px x 64co =
// 4 mfma_32x32x16 tiles. Input slab in LDS [6 rows][34 pos][64ci pad72].
// Weights streamed from global in pre-swizzled A-frag order (L2-hot).
template<int WCO>
__global__ __launch_bounds__(WCO*128) void conv_mfma(const u16* __restrict__ in, const u16* __restrict__ wm,
                                                     const float* __restrict__ bias, u16* __restrict__ out){
  constexpr int COUT = WCO*64;
  constexpr int NCOT = WCO*2;
  constexpr int THREADS = WCO*128;
  constexpr int CO_PAD = COUT + 8;
  constexpr int SLAB = 6*34*72;            // 14688 u16
  constexpr int OT   = 128*CO_PAD;
  __shared__ __align__(16) u16 smem[(SLAB > OT) ? SLAB : OT];

  int tid = threadIdx.x, lane = tid & 63, w = tid >> 6;
  int wr = w & 1, wc = w >> 1;
  int n = lane & 31, kh = lane >> 5;
  int x0 = blockIdx.x*32, y0 = blockIdx.y*4, img = blockIdx.z;
  const u16* inb = in + (size_t)img*HW*64;

  float16 acc[2][2];
  #pragma unroll
  for (int t=0;t<2;t++)
    #pragma unroll
    for (int c=0;c<2;c++)
      #pragma unroll
      for (int k=0;k<16;k++) acc[t][c][k] = 0.f;

  // stage 6x34x64 slab (zeros at borders)
  for (int e = tid; e < 1632; e += THREADS){
    int c8 = e & 7; int pp = e >> 3;
    int row = pp / 34, pos = pp - row*34;
    int gy = y0 + row - 1, gx = x0 + pos - 1;
    uint4 v = make_uint4(0,0,0,0);
    if (gy >= 0 && gy < HH && gx >= 0 && gx < WW)
      v = *(const uint4*)(inb + ((size_t)gy*WW + gx)*64 + c8*8);
    *(uint4*)(smem + pp*72 + c8*8) = v;
  }
  __syncthreads();

  union AU { uint4 q; short8 s; };
  union BU { uint2 u[2]; short8 s; };

  #pragma unroll 1
  for (int ky = 0; ky < 3; ++ky){
    #pragma unroll 1
    for (int kx = 0; kx < 3; ++kx){
      int tap = ky*3 + kx;
      #pragma unroll
      for (int ks = 0; ks < 4; ++ks){
        AU a0, a1;
        const u16* wmp = wm + (((size_t)(tap*4 + ks)*NCOT + wc*2)*64 + lane)*8;
        a0.q = *(const uint4*)(wmp);
        a1.q = *(const uint4*)(wmp + 512);
        #pragma unroll
        for (int t = 0; t < 2; ++t){
          int row = wr*2 + t + ky;
          int off = (row*34 + n + kx)*72 + ks*16 + kh*8;
          BU b;
          b.u[0] = *(const uint2*)(smem + off);
          b.u[1] = *(const uint2*)(smem + off + 4);
          acc[t][0] = __builtin_amdgcn_mfma_f32_32x32x16_bf16(a0.s, b.s, acc[t][0], 0, 0, 0);
          acc[t][1] = __builtin_amdgcn_mfma_f32_32x32x16_bf16(a1.s, b.s, acc[t][1], 0, 0, 0);
        }
      }
    }
  }

  // epilogue: bias + lrelu -> LDS [px][co] -> coalesced NHWC store
  __syncthreads();
  #pragma unroll
  for (int t = 0; t < 2; ++t){
    int pxl = (wr*2 + t)*32 + n;
    #pragma unroll
    for (int c = 0; c < 2; ++c){
      int cob = wc*64 + c*32 + 4*kh;
      #pragma unroll
      for (int p = 0; p < 8; ++p){
        int co = cob + (p&1)*2 + (p>>1)*8;
        float2 bb = *(const float2*)(bias + co);
        float v0 = lrelu(acc[t][c][2*p]   + bb.x);
        float v1 = lrelu(acc[t][c][2*p+1] + bb.y);
        unsigned int pk = (unsigned int)f2b(v0) | ((unsigned int)f2b(v1) << 16);
        *(unsigned int*)(smem + pxl*CO_PAD + co) = pk;
      }
    }
  }
  __syncthreads();
  int px, part;
  if (WCO == 2){ px = tid >> 1; part = tid & 1; } else { px = tid; part = 0; }
  const u16* sp = smem + px*CO_PAD + part*64;
  u16* gp = out + ((size_t)img*HW + (size_t)(y0 + (px>>5))*WW + x0 + (px&31))*COUT + part*64;
  #pragma unroll
  for (int k = 0; k < 8; ++k)
    *(uint4*)(gp + k*8) = *(const uint4*)(sp + k*8);
}

// 1x1 redir conv (128->32) + bias + lrelu. X NCHW [b][473][HW]; planes 0..31.
__global__ __launch_bounds__(256) void redir_k(const u16* __restrict__ C2, const float* __restrict__ wrf,
                                               const float* __restrict__ rbf, u16* __restrict__ X){
  int p = blockIdx.x*256 + threadIdx.x;
  int b = p / HW; int pix = p - b*HW;
  const u16* ap = C2 + (size_t)p*128;
  float acc[32];
  #pragma unroll
  for (int j=0;j<32;j++) acc[j]=0.f;
  for (int ci=0; ci<128; ci+=4){
    uint2 aw = *(const uint2*)(ap + ci);
    float a0,a1,a2,a3;
    up2(aw.x,a0,a1); up2(aw.y,a2,a3);
    const float* w0 = wrf + ci*32;
    #pragma unroll
    for (int co=0; co<32; co+=4){
      float4 wv0 = *(const float4*)(w0+co);
      float4 wv1 = *(const float4*)(w0+32+co);
      float4 wv2 = *(const float4*)(w0+64+co);
      float4 wv3 = *(const float4*)(w0+96+co);
      acc[co+0] += a0*wv0.x + a1*wv1.x + a2*wv2.x + a3*wv3.x;
      acc[co+1] += a0*wv0.y + a1*wv1.y + a2*wv2.y + a3*wv3.y;
      acc[co+2] += a0*wv0.z + a1*wv1.z + a2*wv2.z + a3*wv3.z;
      acc[co+3] += a0*wv0.w + a1*wv1.w + a2*wv2.w + a3*wv3.w;
    }
  }
  #pragma unroll
  for (int co=0; co<32; ++co){
    X[(size_t)(b*473 + co)*HW + pix] = f2b(lrelu(acc[co] + rbf[co]));
  }
}

// Correlation: thread = 1 pixel, block = 1 row, 16-ch chunks, packed bf16 dot2.
#define SEGP 233
__global__ __launch_bounds__(192,4) void corr_k(const u16* __restrict__ C2, u16* __restrict__ X){
  __shared__ __align__(16) uint4 s_seg[2][SEGP];
  int x  = threadIdx.x;
  int y  = blockIdx.x;
  int dy = blockIdx.y;
  int b  = blockIdx.z;
  int r  = y + 2*dy - 20;
  u16* bp0 = X + ((size_t)(b*473 + 32 + dy*21)*HH + y)*WW;
  if (r < 0 || r >= HH){
    #pragma unroll
    for (int dx=0; dx<21; ++dx) bp0[(size_t)dx*HW + x] = 0;
    return;
  }
  const u16* arow = C2 + ((size_t)b*HW + (size_t)y*WW + x)*128;
  const u16* brow = C2 + ((size_t)(b+4)*HW + (size_t)r*WW)*128;
  float acc[21];
  #pragma unroll
  for (int i=0;i<21;i++) acc[i]=0.f;

  for (int c0 = 0; c0 < 128; c0 += 16){
    if (c0) __syncthreads();
    for (int e = x; e < 464; e += 192){
      int g = e & 1, pos = e >> 1;
      int gx = pos - 20;
      uint4 v = make_uint4(0,0,0,0);
      if (gx >= 0 && gx < WW) v = *(const uint4*)(brow + (size_t)gx*128 + c0 + g*8);
      s_seg[g][pos] = v;
    }
    __syncthreads();
    unsigned int av[8];
    *(uint4*)&av[0] = *(const uint4*)(arow + c0);
    *(uint4*)&av[4] = *(const uint4*)(arow + c0 + 8);
    #pragma unroll
    for (int dx = 0; dx < 21; ++dx){
      int pos = x + 2*dx;
      uint4 b0 = s_seg[0][pos];
      uint4 b1 = s_seg[1][pos];
      float a = acc[dx];
      a = dot2bf(av[0], b0.x, a);
      a = dot2bf(av[1], b0.y, a);
      a = dot2bf(av[2], b0.z, a);
      a = dot2bf(av[3], b0.w, a);
      a = dot2bf(av[4], b1.x, a);
      a = dot2bf(av[5], b1.y, a);
      a = dot2bf(av[6], b1.z, a);
      a = dot2bf(av[7], b1.w, a);
      acc[dx] = a;
    }
  }
  #pragma unroll
  for (int dx=0; dx<21; ++dx)
    bp0[(size_t)dx*HW + x] = f2b(lrelu(acc[dx]*(1.f/128.f)));
}

// Final 3x3 conv: contribution-passing (see round 6).
__global__ __launch_bounds__(192) void final_k(const u16* __restrict__ X, const unsigned int* __restrict__ wpb,
                                               void* __restrict__ out, const int* __restrict__ flag){
  __shared__ float eR[4][2], eL[4][2];
  int x = threadIdx.x, y = blockIdx.x, b = blockIdx.y;
  int w = x >> 6, lane = x & 63;
  const u16* Xb = X + (size_t)b*473*HW;
  float Pm0=0.f,Pm1=0.f,Pl0=0.f,Pl1=0.f,Pr0=0.f,Pr1=0.f;
  bool rok0 = (y > 0), rok2 = (y < HH-1);
  size_t off0 = (size_t)(y-1)*WW + x;
  size_t off1 = (size_t)(y  )*WW + x;
  size_t off2 = (size_t)(y+1)*WW + x;

  for (int cp = 0; cp < 237; ++cp){
    const unsigned int* w18 = wpb + cp*18;
    size_t base0 = (size_t)(2*cp)*HW;
    size_t base1 = base0 + HW;
    bool c1ok = (2*cp+1) < 473;
    #pragma unroll
    for (int r = 0; r < 3; ++r){
      bool ok = (r==0) ? rok0 : ((r==2) ? rok2 : true);
      size_t off = (r==0) ? off0 : ((r==2) ? off2 : off1);
      unsigned int v = 0;
      if (ok){
        unsigned int lo = Xb[base0 + off];
        unsigned int hi = c1ok ? (unsigned int)Xb[base1 + off] : 0u;
        v = lo | (hi << 16);
      }
      Pm0 = dot2bf(v, w18[(r*3+1)*2+0], Pm0);
      Pm1 = dot2bf(v, w18[(r*3+1)*2+1], Pm1);
      Pl0 = dot2bf(v, w18[(r*3+2)*2+0], Pl0);
      Pl1 = dot2bf(v, w18[(r*3+2)*2+1], Pl1);
      Pr0 = dot2bf(v, w18[(r*3+0)*2+0], Pr0);
      Pr1 = dot2bf(v, w18[(r*3+0)*2+1], Pr1);
    }
  }

  float r0 = __shfl_up(Pr0,1), r1 = __shfl_up(Pr1,1);
  float l0 = __shfl_down(Pl0,1), l1 = __shfl_down(Pl1,1);
  if (x == 0){ eR[0][0]=0.f; eR[0][1]=0.f; eL[3][0]=0.f; eL[3][1]=0.f; }
  if (lane == 63){ eR[w+1][0]=Pr0; eR[w+1][1]=Pr1; }
  if (lane == 0 && w > 0){ eL[w][0]=Pl0; eL[w][1]=Pl1; }
  __syncthreads();
  if (lane == 0){ r0 = eR[w][0]; r1 = eR[w][1]; }
  if (lane == 63){ l0 = eL[w+1][0]; l1 = eL[w+1][1]; }
  float a0 = Pm0 + r0 + l0;
  float a1 = Pm1 + r1 + l1;

  size_t rem = (size_t)y*WW + x;
  size_t i0 = (size_t)(b*2)*HW + rem;
  size_t i1 = (size_t)(b*2+1)*HW + rem;
  if (*flag){
    ((u16*)out)[i0] = f2b(a0);
    ((u16*)out)[i1] = f2b(a1);
  } else {
    ((float*)out)[i0] = a0;
    ((float*)out)[i1] = a1;
  }
}

// Workspace (bytes):
//   C2 [0, 75497472)           conv2 out NHWC bf16 [8][HW][128]
//   X1 [75497472, 113246208)   cvt out NHWC bf16 [8][HW][64] (dies after conv1)
//   H1 [113246208, 150994944)  conv1 out NHWC bf16 (dies after conv2)
//   X  [75497472, 214958080)   concat NCHW bf16 [4][473][HW] (overlays X1+H1)
//   weights at 215322624 (~260 KB)
extern "C" void kernel_launch(void* const* d_in, const int* in_sizes, int n_in,
                              void* d_out, int out_size, void* d_ws, size_t ws_size,
                              hipStream_t stream){
  char* ws = (char*)d_ws;
  u16* C2 = (u16*)ws;
  u16* X1 = (u16*)(ws + 75497472);
  u16* H1 = (u16*)(ws + 113246208);
  u16* X  = (u16*)(ws + 75497472);
  u16* w1m = (u16*)(ws + 215322624);
  u16* w2m = w1m + 36864;
  float* wrf = (float*)(w2m + 73728);
  unsigned int* wpb = (unsigned int*)(wrf + 4096);
  float* b1f = (float*)(wpb + 4266);
  float* b2f = b1f + 64;
  float* rbf = b2f + 128;
  int* flag  = (int*)(rbf + 32);

  detect_k<<<1,256,0,stream>>>((const unsigned int*)d_in[0], flag);
  cvt_t<<<dim3(576,8),256,0,stream>>>(d_in[0], d_in[1], X1, flag);
  prep_w<<<288,256,0,stream>>>(d_in[2], d_in[4], d_in[6], d_in[8],
                               d_in[3], d_in[5], d_in[7],
                               w1m, w2m, wrf, wpb, b1f, b2f, rbf, flag);
  conv_mfma<1><<<dim3(6,48,8),128,0,stream>>>(X1, w1m, b1f, H1);
  conv_mfma<2><<<dim3(6,48,8),256,0,stream>>>(H1, w2m, b2f, C2);
  redir_k<<<576,256,0,stream>>>(C2, wrf, rbf, X);
  corr_k<<<dim3(192,21,4),192,0,stream>>>(C2, X);
  final_k<<<dim3(192,4),192,0,stream>>>(X, wpb, d_out, flag);
}